// Round 8
// baseline (1051.691 us; speedup 1.0000x reference)
//
#include <hip/hip_runtime.h>

#define N0c 262144
#define INc 128
#define Hc  32
#define N1c 131072
#define N2c 65536
#define E0c 2097152
#define E1c 1048576

__device__ __forceinline__ void fma4(float4& a, float s, const float4 w) {
    a.x = fmaf(s, w.x, a.x);
    a.y = fmaf(s, w.y, a.y);
    a.z = fmaf(s, w.z, a.z);
    a.w = fmaf(s, w.w, a.w);
}

__device__ __forceinline__ unsigned short f2bf(float f) {
    unsigned u = __float_as_uint(f);
    u += 0x7fffu + ((u >> 16) & 1u);          // round-to-nearest-even
    return (unsigned short)(u >> 16);
}
__device__ __forceinline__ ushort4 pack4(float4 v) {
    return make_ushort4(f2bf(v.x), f2bf(v.y), f2bf(v.z), f2bf(v.w));
}
__device__ __forceinline__ float bflo(unsigned u) { return __uint_as_float(u << 16); }
__device__ __forceinline__ float bfhi(unsigned u) { return __uint_as_float(u & 0xffff0000u); }

// ---------------- layer-0 linear, single-output: out = x @ w^T ----------------
// 256 threads, 128 rows/block, K=128 in 4 chunks. LDS 20 KB, one acc set -> no spill.
// outb != null -> write bf16, else write fp32 to outf.
__global__ __launch_bounds__(256) void lin0_one_kernel(
    const float* __restrict__ x, const float* __restrict__ w,
    unsigned short* __restrict__ outb, float* __restrict__ outf)
{
    __shared__ float xs[128 * 32];
    __shared__ float ws[32 * 32];
    const int t = threadIdx.x;
    const int rowBase = blockIdx.x * 128;
    const int cg = t & 7;
    const int rg = t >> 3;

    float4* xs4w = (float4*)xs;
    const float4* xs4 = (const float4*)xs;
    const float4* ws4 = (const float4*)ws;

    float4 acc[4];
#pragma unroll
    for (int i = 0; i < 4; ++i) acc[i] = make_float4(0.f, 0.f, 0.f, 0.f);

    for (int kc = 0; kc < 4; ++kc) {
        if (kc) __syncthreads();
#pragma unroll
        for (int i = 0; i < 4; ++i) {
            int idx = t + 256 * i;
            int row = idx >> 3, kq = idx & 7;
            float4 v = ((const float4*)x)[(rowBase + row) * 32 + kc * 8 + kq];
            xs4w[row * 8 + ((kq + (row >> 2)) & 7)] = v;
        }
#pragma unroll
        for (int i = 0; i < 4; ++i) {
            int idx = t + 256 * i;
            int kk = idx & 31, j = idx >> 5;
            int dst = kk * 32 + 4 * (((j >> 2) + kk) & 7) + (j & 3);
            ws[dst] = w[j * 128 + kc * 32 + kk];
        }
        __syncthreads();

#pragma unroll
        for (int kq = 0; kq < 8; ++kq) {
            float4 xv[4];
#pragma unroll
            for (int i = 0; i < 4; ++i)
                xv[i] = xs4[(4 * rg + i) * 8 + ((kq + rg) & 7)];
            const int kb = 4 * kq;
            float4 w0 = ws4[(kb + 0) * 8 + ((cg + kb + 0) & 7)];
            float4 w1 = ws4[(kb + 1) * 8 + ((cg + kb + 1) & 7)];
            float4 w2 = ws4[(kb + 2) * 8 + ((cg + kb + 2) & 7)];
            float4 w3 = ws4[(kb + 3) * 8 + ((cg + kb + 3) & 7)];
#pragma unroll
            for (int i = 0; i < 4; ++i) {
                fma4(acc[i], xv[i].x, w0);
                fma4(acc[i], xv[i].y, w1);
                fma4(acc[i], xv[i].z, w2);
                fma4(acc[i], xv[i].w, w3);
            }
        }
    }

    if (outb) {
#pragma unroll
        for (int i = 0; i < 4; ++i) {
            int r = rowBase + 4 * rg + i;
            ((ushort4*)outb)[r * 8 + cg] = pack4(acc[i]);
        }
    } else {
#pragma unroll
        for (int i = 0; i < 4; ++i) {
            int r = rowBase + 4 * rg + i;
            ((float4*)outf)[r * 8 + cg] = acc[i];
        }
    }
}

// ---------------- layer-1 linear: K=32, 64 rows/block; y bf16, z fp32 ----------------
__global__ __launch_bounds__(128) void lin1_kernel(
    const float* __restrict__ h, const float* __restrict__ wl,
    const float* __restrict__ wr, unsigned short* __restrict__ y,
    float* __restrict__ z)
{
    __shared__ float xs[64 * 32];
    __shared__ float wls[32 * 32];
    __shared__ float wrs[32 * 32];
    const int t = threadIdx.x;
    const long rowBase = (long)blockIdx.x * 64;
    const bool doZ = rowBase < N2c;

#pragma unroll
    for (int i = 0; i < 8; ++i) {
        int idx = t + 128 * i;
        int j = idx >> 5, k = idx & 31;
        int dst = k * 32 + 4 * (((j >> 2) + k) & 7) + (j & 3);
        wls[dst] = wl[idx];
        if (doZ) wrs[dst] = wr[idx];
    }
#pragma unroll
    for (int i = 0; i < 4; ++i) {
        int idx = t + 128 * i;
        int row = idx >> 3, k4 = idx & 7;
        float4 v = ((const float4*)h)[rowBase * 8 + idx];
        ((float4*)xs)[row * 8 + ((k4 + (row >> 2)) & 7)] = v;
    }
    __syncthreads();

    const int cg = t & 7;
    const int rg = t >> 3;
    const float4* xs4  = (const float4*)xs;
    const float4* wls4 = (const float4*)wls;
    const float4* wrs4 = (const float4*)wrs;

    float4 accY[4], accZ[4];
#pragma unroll
    for (int i = 0; i < 4; ++i) {
        accY[i] = make_float4(0.f, 0.f, 0.f, 0.f);
        accZ[i] = make_float4(0.f, 0.f, 0.f, 0.f);
    }

#pragma unroll
    for (int k4 = 0; k4 < 8; ++k4) {
        float4 xv[4];
#pragma unroll
        for (int i = 0; i < 4; ++i)
            xv[i] = xs4[(4 * rg + i) * 8 + ((k4 + rg) & 7)];
        const int kb = 4 * k4;
        float4 w0 = wls4[(kb + 0) * 8 + ((cg + kb + 0) & 7)];
        float4 w1 = wls4[(kb + 1) * 8 + ((cg + kb + 1) & 7)];
        float4 w2 = wls4[(kb + 2) * 8 + ((cg + kb + 2) & 7)];
        float4 w3 = wls4[(kb + 3) * 8 + ((cg + kb + 3) & 7)];
#pragma unroll
        for (int i = 0; i < 4; ++i) {
            fma4(accY[i], xv[i].x, w0);
            fma4(accY[i], xv[i].y, w1);
            fma4(accY[i], xv[i].z, w2);
            fma4(accY[i], xv[i].w, w3);
        }
        if (doZ) {
            float4 u0 = wrs4[(kb + 0) * 8 + ((cg + kb + 0) & 7)];
            float4 u1 = wrs4[(kb + 1) * 8 + ((cg + kb + 1) & 7)];
            float4 u2 = wrs4[(kb + 2) * 8 + ((cg + kb + 2) & 7)];
            float4 u3 = wrs4[(kb + 3) * 8 + ((cg + kb + 3) & 7)];
#pragma unroll
            for (int i = 0; i < 4; ++i) {
                fma4(accZ[i], xv[i].x, u0);
                fma4(accZ[i], xv[i].y, u1);
                fma4(accZ[i], xv[i].z, u2);
                fma4(accZ[i], xv[i].w, u3);
            }
        }
    }
#pragma unroll
    for (int i = 0; i < 4; ++i) {
        long r = rowBase + 4 * rg + i;
        ((ushort4*)y)[r * 8 + cg] = pack4(accY[i]);
        if (doZ) ((float4*)z)[r * 8 + cg] = accZ[i];
    }
}

// ---------------- bucket histogram: LDS per-block, <=256 global atomics/block ----------------
__global__ __launch_bounds__(256) void bhist_kernel(
    const int* __restrict__ tgt, int* __restrict__ bcnt, int nb)
{
    __shared__ int hist[256];
    const int t = threadIdx.x;
    const int base = blockIdx.x * 8192;
    hist[t] = 0;
    __syncthreads();
#pragma unroll 4
    for (int i = 0; i < 32; ++i)
        atomicAdd(&hist[tgt[base + i * 256 + t] >> 9], 1);
    __syncthreads();
    if (t < nb && hist[t]) atomicAdd(&bcnt[t], hist[t]);
}

// ---------------- bucket scan: one block, exclusive scan of nb bucket counts ----------------
__global__ __launch_bounds__(256) void bscan_kernel(
    const int* __restrict__ bcnt, int* __restrict__ bbase,
    int* __restrict__ bcur, int nb, int nE)
{
    __shared__ int s[256];
    int t = threadIdx.x;
    int local = (t < nb) ? bcnt[t] : 0;
    s[t] = local;
    __syncthreads();
    int v = local;
#pragma unroll
    for (int off = 1; off < 256; off <<= 1) {
        int u = (t >= off) ? s[t - off] : 0;
        __syncthreads();
        v += u;
        s[t] = v;
        __syncthreads();
    }
    int ex = v - local;
    if (t < nb) {
        bbase[t] = ex;
        bcur[t] = ex;
    }
    if (t == nb - 1) bbase[nb] = nE;
}

// ---------------- partition: multisplit edges into 512-target buckets ----------------
__global__ __launch_bounds__(256) void part_kernel(
    const int* __restrict__ src, const int* __restrict__ tgt,
    int2* __restrict__ pairs, int* __restrict__ bcur, int nb)
{
    __shared__ int hist[256];
    __shared__ int bbase[256];
    const int t = threadIdx.x;
    const int base = blockIdx.x * 8192;
    hist[t] = 0;
    __syncthreads();
#pragma unroll 4
    for (int i = 0; i < 32; ++i) {
        int e = base + i * 256 + t;
        atomicAdd(&hist[tgt[e] >> 9], 1);
    }
    __syncthreads();
    if (t < nb) bbase[t] = atomicAdd(&bcur[t], hist[t]);
    __syncthreads();
    hist[t] = 0;
    __syncthreads();
#pragma unroll 4
    for (int i = 0; i < 32; ++i) {
        int e = base + i * 256 + t;
        int tv = tgt[e], sv = src[e];
        int b = tv >> 9;
        int r = atomicAdd(&hist[b], 1);
        pairs[bbase[b] + r] = make_int2(sv, tv);
    }
}

// ---------------- fused bucket aggregation + epilogue ----------------
// One block per bucket (512 targets). Accumulate y[src] rows (bf16) into LDS
// agg[512][33] via workgroup-scope float atomics; then mean+bias+root+L2norm
// (+relu) and coalesced store. Replaces sortb + gather_agg (no eidx/cnt/cur).
#define AGG_S 33
__global__ __launch_bounds__(1024) void bucket_agg_kernel(
    const int2* __restrict__ pairs, const int* __restrict__ bbase,
    const unsigned short* __restrict__ y, const float* __restrict__ z,
    const float* __restrict__ bias, float* __restrict__ out, int doRelu)
{
    __shared__ float agg[512 * AGG_S];   // ~67.6 KB, stride 33 breaks bank conflicts
    __shared__ int ccnt[512];
    const int t = threadIdx.x;
    const int b = blockIdx.x;
    const int tlo = b << 9;
    const int beg = bbase[b];
    const int end = bbase[b + 1];

    for (int i = t; i < 512 * AGG_S; i += 1024) agg[i] = 0.f;
    if (t < 512) ccnt[t] = 0;
    __syncthreads();

    for (int e = beg + t; e < end; e += 1024) {
        int2 p = pairs[e];
        int li = p.y - tlo;
        atomicAdd(&ccnt[li], 1);
        const uint4* yr = (const uint4*)(y + (long)p.x * 32);
        float* ar = &agg[li * AGG_S];
#pragma unroll
        for (int j = 0; j < 4; ++j) {
            uint4 q = yr[j];          // 16 B = 8 bf16 values
            float* a8 = ar + j * 8;
            __hip_atomic_fetch_add(a8 + 0, bflo(q.x), __ATOMIC_RELAXED, __HIP_MEMORY_SCOPE_WORKGROUP);
            __hip_atomic_fetch_add(a8 + 1, bfhi(q.x), __ATOMIC_RELAXED, __HIP_MEMORY_SCOPE_WORKGROUP);
            __hip_atomic_fetch_add(a8 + 2, bflo(q.y), __ATOMIC_RELAXED, __HIP_MEMORY_SCOPE_WORKGROUP);
            __hip_atomic_fetch_add(a8 + 3, bfhi(q.y), __ATOMIC_RELAXED, __HIP_MEMORY_SCOPE_WORKGROUP);
            __hip_atomic_fetch_add(a8 + 4, bflo(q.z), __ATOMIC_RELAXED, __HIP_MEMORY_SCOPE_WORKGROUP);
            __hip_atomic_fetch_add(a8 + 5, bfhi(q.z), __ATOMIC_RELAXED, __HIP_MEMORY_SCOPE_WORKGROUP);
            __hip_atomic_fetch_add(a8 + 6, bflo(q.w), __ATOMIC_RELAXED, __HIP_MEMORY_SCOPE_WORKGROUP);
            __hip_atomic_fetch_add(a8 + 7, bfhi(q.w), __ATOMIC_RELAXED, __HIP_MEMORY_SCOPE_WORKGROUP);
        }
    }
    __syncthreads();

    const int part = t & 7;
    const int rloc = t >> 3;             // 0..127
    const float4 bb = ((const float4*)bias)[part];
    const float4* z4 = (const float4*)z;
    float4* o4 = (float4*)out;
#pragma unroll
    for (int r0 = 0; r0 < 512; r0 += 128) {
        int row = r0 + rloc;
        long g = tlo + row;
        float inv = 1.f / fmaxf((float)ccnt[row], 1.f);
        const float* ar = &agg[row * AGG_S + part * 4];
        float4 zz = z4[g * 8 + part];
        float4 v;
        v.x = fmaf(ar[0], inv, bb.x) + zz.x;
        v.y = fmaf(ar[1], inv, bb.y) + zz.y;
        v.z = fmaf(ar[2], inv, bb.z) + zz.z;
        v.w = fmaf(ar[3], inv, bb.w) + zz.w;
        float ss = v.x * v.x + v.y * v.y + v.z * v.z + v.w * v.w;
        ss += __shfl_xor(ss, 1);
        ss += __shfl_xor(ss, 2);
        ss += __shfl_xor(ss, 4);
        float q = 1.f / fmaxf(sqrtf(ss), 1e-12f);
        v.x *= q; v.y *= q; v.z *= q; v.w *= q;
        if (doRelu) {
            v.x = fmaxf(v.x, 0.f); v.y = fmaxf(v.y, 0.f);
            v.z = fmaxf(v.z, 0.f); v.w = fmaxf(v.w, 0.f);
        }
        o4[g * 8 + part] = v;
    }
}

extern "C" void kernel_launch(void* const* d_in, const int* in_sizes, int n_in,
                              void* d_out, int out_size, void* d_ws, size_t ws_size,
                              hipStream_t stream) {
    const float* x   = (const float*)d_in[0];
    const int* src0  = (const int*)d_in[1];
    const int* tgt0  = (const int*)d_in[2];
    const int* src1  = (const int*)d_in[3];
    const int* tgt1  = (const int*)d_in[4];
    const float* wl0 = (const float*)d_in[5];
    const float* bl0 = (const float*)d_in[6];
    const float* wr0 = (const float*)d_in[7];
    const float* wl1 = (const float*)d_in[8];
    const float* bl1 = (const float*)d_in[9];
    const float* wr1 = (const float*)d_in[10];

    char* W = (char*)d_ws;
    unsigned short* y0 = (unsigned short*)(W + 0);          // 16 MB (bf16)
    float*  z0    = (float*) (W + 16777216);                // 16 MB
    int2*   pairs0= (int2*)  (W + 33554432);                // 16 MB
    float*  h     = (float*) (W + 50331648);                // 16 MB
    unsigned short* y1 = (unsigned short*)(W + 67108864);   //  8 MB (bf16)
    float*  z1    = (float*) (W + 75497472);                //  8 MB
    int2*   pairs1= (int2*)  (W + 83886080);                //  8 MB
    int*    bcnt  = (int*)   (W + 92274688);                //  1 KB
    int*    bbase = (int*)   (W + 92275712);                //  2 KB (257 ints)
    int*    bcur  = (int*)   (W + 92277760);                //  1 KB

    // ---- layer 0 ----
    hipMemsetAsync(bcnt, 0, 1024, stream);
    lin0_one_kernel<<<N0c / 128, 256, 0, stream>>>(x, wl0, y0, nullptr);
    lin0_one_kernel<<<N1c / 128, 256, 0, stream>>>(x, wr0, nullptr, z0);
    bhist_kernel<<<E0c / 8192, 256, 0, stream>>>(tgt0, bcnt, 256);
    bscan_kernel<<<1, 256, 0, stream>>>(bcnt, bbase, bcur, 256, E0c);
    part_kernel<<<E0c / 8192, 256, 0, stream>>>(src0, tgt0, pairs0, bcur, 256);
    bucket_agg_kernel<<<256, 1024, 0, stream>>>(pairs0, bbase, y0, z0, bl0, h, 1);

    // ---- layer 1 ----
    hipMemsetAsync(bcnt, 0, 1024, stream);
    bhist_kernel<<<E1c / 8192, 256, 0, stream>>>(tgt1, bcnt, 128);
    bscan_kernel<<<1, 256, 0, stream>>>(bcnt, bbase, bcur, 128, E1c);
    part_kernel<<<E1c / 8192, 256, 0, stream>>>(src1, tgt1, pairs1, bcur, 128);
    lin1_kernel<<<N1c / 64, 128, 0, stream>>>(h, wl1, wr1, y1, z1);
    bucket_agg_kernel<<<128, 1024, 0, stream>>>(pairs1, bbase, y1, z1, bl1,
                                                (float*)d_out, 0);
}